// Round 1
// baseline (435.162 us; speedup 1.0000x reference)
//
#include <hip/hip_runtime.h>

#define NN 10000
#define NE 320000
#define ROW_WORDS 320   // 320*32 = 10240 bits >= 10000

// ---------------- degree via dedup bitmap ----------------

__global__ void scatter_bits(const int* __restrict__ ei, unsigned int* __restrict__ bitmap) {
    int t = blockIdx.x * blockDim.x + threadIdx.x;
    if (t < NE) {
        int i = ei[t];
        int j = ei[NE + t];
        atomicOr(&bitmap[i * ROW_WORDS + (j >> 5)], 1u << (j & 31));
    } else if (t < NE + NN) {
        int i = t - NE;
        atomicOr(&bitmap[i * ROW_WORDS + (i >> 5)], 1u << (i & 31));
    }
}

__global__ void degree_kernel(const unsigned int* __restrict__ bitmap, float* __restrict__ deg) {
    int wave = threadIdx.x >> 6;
    int lane = threadIdx.x & 63;
    int row = blockIdx.x * 4 + wave;
    if (row >= NN) return;
    int cnt = 0;
    for (int w = lane; w < ROW_WORDS; w += 64)
        cnt += __popc(bitmap[row * ROW_WORDS + w]);
    #pragma unroll
    for (int off = 32; off > 0; off >>= 1)
        cnt += __shfl_down(cnt, off, 64);
    if (lane == 0) deg[row] = (float)cnt;
}

// ---------------- GEMM: C = relu((deg?deg⊙A:A) @ W + bias) ----------------

#define BM 64
#define BN 64
#define BK 16

__global__ __launch_bounds__(256)
void gemm_bias_relu(const float* __restrict__ A, const float* __restrict__ W,
                    const float* __restrict__ bias, const float* __restrict__ deg,
                    float* __restrict__ C, int M, int N, int K) {
    __shared__ float As[BK][BM + 1];
    __shared__ float Ws[BK][BN];
    int t = threadIdx.x;
    int tx = t & 15, ty = t >> 4;
    int row0 = blockIdx.y * BM, col0 = blockIdx.x * BN;
    float acc[4][4] = {};
    for (int k0 = 0; k0 < K; k0 += BK) {
        #pragma unroll
        for (int p = 0; p < 4; ++p) {
            int r = (t >> 4) + p * 16;
            int k = t & 15;
            int gr = row0 + r, gk = k0 + k;
            float v = 0.f;
            if (gr < M && gk < K) {
                v = A[(long)gr * K + gk];
                if (deg) v *= deg[gr];
            }
            As[k][r] = v;
        }
        #pragma unroll
        for (int p = 0; p < 4; ++p) {
            int idx = t + p * 256;
            int k = idx >> 6, c = idx & 63;
            int gk = k0 + k, gc = col0 + c;
            Ws[k][c] = (gk < K && gc < N) ? W[(long)gk * N + gc] : 0.f;
        }
        __syncthreads();
        #pragma unroll
        for (int kk = 0; kk < BK; ++kk) {
            float a[4], w[4];
            #pragma unroll
            for (int i = 0; i < 4; ++i) a[i] = As[kk][ty + 16 * i];
            #pragma unroll
            for (int j = 0; j < 4; ++j) w[j] = Ws[kk][tx + 16 * j];
            #pragma unroll
            for (int i = 0; i < 4; ++i)
                #pragma unroll
                for (int j = 0; j < 4; ++j)
                    acc[i][j] += a[i] * w[j];
        }
        __syncthreads();
    }
    #pragma unroll
    for (int i = 0; i < 4; ++i) {
        int gr = row0 + ty + 16 * i;
        if (gr >= M) continue;
        #pragma unroll
        for (int j = 0; j < 4; ++j) {
            int gc = col0 + tx + 16 * j;
            if (gc >= N) continue;
            float v = acc[i][j] + bias[gc];
            C[(long)gr * N + gc] = v > 0.f ? v : 0.f;
        }
    }
}

// ---------------- BatchNorm (training-mode batch stats) ----------------

// block of N threads; each thread owns one column over a chunk of rows
__global__ void bn_stats(const float* __restrict__ H, float* __restrict__ stats,
                         int M, int N, int rows_per_blk) {
    int j = threadIdx.x;
    int r0 = blockIdx.x * rows_per_blk;
    int r1 = r0 + rows_per_blk; if (r1 > M) r1 = M;
    float s = 0.f, ss = 0.f;
    for (int r = r0; r < r1; ++r) {
        float v = H[(long)r * N + j];
        s += v; ss += v * v;
    }
    atomicAdd(&stats[j], s);
    atomicAdd(&stats[N + j], ss);
}

__global__ void bn_coeff(const float* __restrict__ stats, const float* __restrict__ g,
                         const float* __restrict__ b, float* __restrict__ coeff,
                         int M, int N) {
    int j = threadIdx.x;
    if (j >= N) return;
    float mean = stats[j] / (float)M;
    float var  = stats[N + j] / (float)M - mean * mean;
    float sc = g[j] * rsqrtf(var + 1e-5f);
    coeff[j] = sc;
    coeff[N + j] = b[j] - mean * sc;
}

__global__ void bn_apply(float* __restrict__ H, const float* __restrict__ coeff, int M, int N) {
    int idx = blockIdx.x * blockDim.x + threadIdx.x;
    if (idx >= M * N) return;
    int j = idx & (N - 1);   // N is 256 here (power of 2)
    H[idx] = H[idx] * coeff[j] + coeff[N + j];
}

// ---------------- launch ----------------

extern "C" void kernel_launch(void* const* d_in, const int* in_sizes, int n_in,
                              void* d_out, int out_size, void* d_ws, size_t ws_size,
                              hipStream_t stream) {
    const float* x     = (const float*)d_in[0];
    const int*   ei    = (const int*)d_in[1];
    const float* W0    = (const float*)d_in[2];
    const float* b0    = (const float*)d_in[3];
    const float* g0    = (const float*)d_in[4];
    const float* bb0   = (const float*)d_in[5];
    const float* W1    = (const float*)d_in[6];
    const float* b1    = (const float*)d_in[7];
    const float* g1    = (const float*)d_in[8];
    const float* bb1   = (const float*)d_in[9];
    const float* fW0   = (const float*)d_in[10];
    const float* fb0   = (const float*)d_in[11];
    const float* fW1   = (const float*)d_in[12];
    const float* fb1   = (const float*)d_in[13];
    float* out = (float*)d_out;

    char* ws = (char*)d_ws;
    unsigned int* bitmap = (unsigned int*)ws;            ws += (size_t)NN * ROW_WORDS * 4;  // 12.8 MB
    float* deg   = (float*)ws;                           ws += NN * 4;
    float* H1    = (float*)ws;                           ws += (size_t)NN * 256 * 4;
    float* H2    = (float*)ws;                           ws += (size_t)NN * 256 * 4;
    float* H3    = (float*)ws;                           ws += (size_t)NN * 128 * 4;
    float* stats = (float*)ws;                           ws += 512 * 4;
    float* coeff = (float*)ws;                           ws += 512 * 4;

    // degree
    hipMemsetAsync(bitmap, 0, (size_t)NN * ROW_WORDS * 4, stream);
    scatter_bits<<<(NE + NN + 255) / 256, 256, 0, stream>>>(ei, bitmap);
    degree_kernel<<<(NN + 3) / 4, 256, 0, stream>>>(bitmap, deg);

    const int M = NN;
    dim3 blk(256);

    // conv0: H1 = relu((deg⊙x) @ W0 + b0), then BN
    gemm_bias_relu<<<dim3(4, (M + BM - 1) / BM), blk, 0, stream>>>(x, W0, b0, deg, H1, M, 256, 500);
    hipMemsetAsync(stats, 0, 512 * 4, stream);
    bn_stats<<<64, 256, 0, stream>>>(H1, stats, M, 256, (M + 63) / 64);
    bn_coeff<<<1, 256, 0, stream>>>(stats, g0, bb0, coeff, M, 256);
    bn_apply<<<(M * 256 + 255) / 256, blk, 0, stream>>>(H1, coeff, M, 256);

    // conv1: H2 = relu((deg⊙H1) @ W1 + b1), then BN
    gemm_bias_relu<<<dim3(4, (M + BM - 1) / BM), blk, 0, stream>>>(H1, W1, b1, deg, H2, M, 256, 256);
    hipMemsetAsync(stats, 0, 512 * 4, stream);
    bn_stats<<<64, 256, 0, stream>>>(H2, stats, M, 256, (M + 63) / 64);
    bn_coeff<<<1, 256, 0, stream>>>(stats, g1, bb1, coeff, M, 256);
    bn_apply<<<(M * 256 + 255) / 256, blk, 0, stream>>>(H2, coeff, M, 256);

    // fc0: H3 = relu(H2 @ fW0 + fb0)
    gemm_bias_relu<<<dim3(2, (M + BM - 1) / BM), blk, 0, stream>>>(H2, fW0, fb0, nullptr, H3, M, 128, 256);
    // fc1: out = relu(H3 @ fW1 + fb1)
    gemm_bias_relu<<<dim3(1, (M + BM - 1) / BM), blk, 0, stream>>>(H3, fW1, fb1, nullptr, out, M, 40, 128);
}

// Round 2
// 261.728 us; speedup vs baseline: 1.6626x; 1.6626x over previous
//
#include <hip/hip_runtime.h>

#define NN 10000
#define NE 320000
#define ROW_WORDS 320   // 320*32 = 10240 bits >= 10000

typedef __attribute__((ext_vector_type(8))) short short8;
typedef __attribute__((ext_vector_type(4))) float f32x4;

// ---------------- degree via dedup bitmap ----------------

__global__ void scatter_bits(const int* __restrict__ ei, unsigned int* __restrict__ bitmap) {
    int t = blockIdx.x * blockDim.x + threadIdx.x;
    if (t < NE) {
        int i = ei[t];
        int j = ei[NE + t];
        atomicOr(&bitmap[i * ROW_WORDS + (j >> 5)], 1u << (j & 31));
    } else if (t < NE + NN) {
        int i = t - NE;
        atomicOr(&bitmap[i * ROW_WORDS + (i >> 5)], 1u << (i & 31));
    }
}

__global__ void degree_kernel(const unsigned int* __restrict__ bitmap, float* __restrict__ deg) {
    int wave = threadIdx.x >> 6;
    int lane = threadIdx.x & 63;
    int row = blockIdx.x * 4 + wave;
    if (row >= NN) return;
    int cnt = 0;
    for (int w = lane; w < ROW_WORDS; w += 64)
        cnt += __popc(bitmap[row * ROW_WORDS + w]);
    #pragma unroll
    for (int off = 32; off > 0; off >>= 1)
        cnt += __shfl_down(cnt, off, 64);
    if (lane == 0) deg[row] = (float)cnt;
}

// ---------------- split-bf16 helper ----------------
// v = hi + lo + eps, |eps| <~ 2^-16 |v|. Truncation keeps (v - hi) exact in fp32.
__device__ inline void split_bf16(float v, unsigned short& hi, unsigned short& lo) {
    unsigned int u = __float_as_uint(v);
    hi = (unsigned short)(u >> 16);
    float hf = __uint_as_float(u & 0xFFFF0000u);
    lo = (unsigned short)(__float_as_uint(v - hf) >> 16);
}

// ---------------- fused GEMM:
//   C = relu( (deg ⊙ (A*sc + sh)) @ W + bias ),  optional column stats Σv, Σv²
// Tile: BM=128, BN=64, BK=32. 256 threads = 4 waves, wave w owns rows [32w,32w+32).
// 3-MFMA split-bf16 per (frag pair): fp32-class accuracy at bf16 MFMA rate.
__global__ __launch_bounds__(256, 2)
void gemm_fused(const float* __restrict__ A, const float* __restrict__ W,
                const float* __restrict__ bias,
                const float* __restrict__ deg,       // nullable: row scale
                const float* __restrict__ sc,        // nullable: BN scale  (len K)
                const float* __restrict__ sh,        // nullable: BN shift  (len K)
                float* __restrict__ C,
                float* __restrict__ stats,           // nullable: [N] sums, [N..2N) sumsq
                int M, int N, int K) {
    __shared__ unsigned short As_h[128 * 40];
    __shared__ unsigned short As_l[128 * 40];
    __shared__ unsigned short Bs_h[64 * 40];
    __shared__ unsigned short Bs_l[64 * 40];

    const int t = threadIdx.x;
    const int lane = t & 63;
    const int w = t >> 6;           // wave id 0..3
    const int q = lane >> 4;        // quad 0..3
    const int l16 = lane & 15;
    const int row0 = blockIdx.y * 128;
    const int col0 = blockIdx.x * 64;

    f32x4 acc[2][4];
    #pragma unroll
    for (int g = 0; g < 2; ++g)
        #pragma unroll
        for (int s = 0; s < 4; ++s)
            acc[g][s] = (f32x4){0.f, 0.f, 0.f, 0.f};

    // staging thread mapping
    const int ar = t >> 3;          // A: row 0..31 (+32p)
    const int af = t & 7;           // A: float4 slot (k = af*4)
    const int bn = t & 63;          // B: local col
    const int bk0 = (t >> 6) * 8;   // B: k sub-block {0,8,16,24}

    for (int k0 = 0; k0 < K; k0 += 32) {
        // ---- stage A: 128 x 32 fp32 -> split bf16 (row-major, pitch 40) ----
        #pragma unroll
        for (int p = 0; p < 4; ++p) {
            int r = ar + 32 * p;
            int gr = row0 + r;
            int gk = k0 + af * 4;
            float vals[4] = {0.f, 0.f, 0.f, 0.f};
            if (gr < M && gk + 4 <= K) {
                const float* ap = A + (size_t)gr * K + gk;
                float4 v = *(const float4*)ap;
                float d = deg ? deg[gr] : 1.f;
                vals[0] = v.x; vals[1] = v.y; vals[2] = v.z; vals[3] = v.w;
                if (sc) {
                    #pragma unroll
                    for (int i = 0; i < 4; ++i) vals[i] = fmaf(vals[i], sc[gk + i], sh[gk + i]);
                }
                #pragma unroll
                for (int i = 0; i < 4; ++i) vals[i] *= d;
            }
            ushort4 hs, ls;
            split_bf16(vals[0], hs.x, ls.x);
            split_bf16(vals[1], hs.y, ls.y);
            split_bf16(vals[2], hs.z, ls.z);
            split_bf16(vals[3], hs.w, ls.w);
            *(ushort4*)&As_h[r * 40 + af * 4] = hs;
            *(ushort4*)&As_l[r * 40 + af * 4] = ls;
        }
        // ---- stage B: 32 x 64 fp32 -> split bf16, transposed (col-major, pitch 40) ----
        {
            int gc = col0 + bn;
            unsigned short hs[8], ls[8];
            #pragma unroll
            for (int j = 0; j < 8; ++j) {
                int gk = k0 + bk0 + j;
                float x = 0.f;
                if (gk < K && gc < N) x = W[(size_t)gk * N + gc];
                split_bf16(x, hs[j], ls[j]);
            }
            *(short8*)&Bs_h[bn * 40 + bk0] = *(short8*)hs;
            *(short8*)&Bs_l[bn * 40 + bk0] = *(short8*)ls;
        }
        __syncthreads();

        // ---- fragments + MFMA ----
        short8 ah[2], al[2], bh[4], bl[4];
        #pragma unroll
        for (int g = 0; g < 2; ++g) {
            int off = (32 * w + 16 * g + l16) * 40 + 8 * q;
            ah[g] = *(const short8*)&As_h[off];
            al[g] = *(const short8*)&As_l[off];
        }
        #pragma unroll
        for (int s = 0; s < 4; ++s) {
            int off = (16 * s + l16) * 40 + 8 * q;
            bh[s] = *(const short8*)&Bs_h[off];
            bl[s] = *(const short8*)&Bs_l[off];
        }
        #pragma unroll
        for (int g = 0; g < 2; ++g)
            #pragma unroll
            for (int s = 0; s < 4; ++s) {
                acc[g][s] = __builtin_amdgcn_mfma_f32_16x16x32_bf16(al[g], bh[s], acc[g][s], 0, 0, 0);
                acc[g][s] = __builtin_amdgcn_mfma_f32_16x16x32_bf16(ah[g], bl[s], acc[g][s], 0, 0, 0);
                acc[g][s] = __builtin_amdgcn_mfma_f32_16x16x32_bf16(ah[g], bh[s], acc[g][s], 0, 0, 0);
            }
        __syncthreads();
    }

    // ---- epilogue: bias + relu + store + column stats ----
    #pragma unroll
    for (int g = 0; g < 2; ++g)
        #pragma unroll
        for (int s = 0; s < 4; ++s) {
            int gc = col0 + 16 * s + l16;
            float b_ = (gc < N) ? bias[gc] : 0.f;
            float s_sum = 0.f, ss_sum = 0.f;
            #pragma unroll
            for (int r = 0; r < 4; ++r) {
                int grow = row0 + 32 * w + 16 * g + q * 4 + r;
                float v = acc[g][s][r] + b_;
                v = v > 0.f ? v : 0.f;
                if (grow < M && gc < N) {
                    C[(size_t)grow * N + gc] = v;
                    s_sum += v;
                    ss_sum += v * v;
                }
            }
            if (stats) {
                s_sum += __shfl_xor(s_sum, 16);
                s_sum += __shfl_xor(s_sum, 32);
                ss_sum += __shfl_xor(ss_sum, 16);
                ss_sum += __shfl_xor(ss_sum, 32);
                if (lane < 16 && gc < N) {
                    atomicAdd(&stats[gc], s_sum);
                    atomicAdd(&stats[N + gc], ss_sum);
                }
            }
        }
}

// ---------------- BN coefficients from accumulated stats ----------------
__global__ void bn_coeff(const float* __restrict__ stats, const float* __restrict__ g,
                         const float* __restrict__ b, float* __restrict__ coeff,
                         int M, int N) {
    int j = threadIdx.x;
    if (j >= N) return;
    float mean = stats[j] / (float)M;
    float var  = stats[N + j] / (float)M - mean * mean;
    float scl = g[j] * rsqrtf(var + 1e-5f);
    coeff[j] = scl;
    coeff[N + j] = b[j] - mean * scl;
}

// ---------------- launch ----------------

extern "C" void kernel_launch(void* const* d_in, const int* in_sizes, int n_in,
                              void* d_out, int out_size, void* d_ws, size_t ws_size,
                              hipStream_t stream) {
    const float* x   = (const float*)d_in[0];
    const int*   ei  = (const int*)d_in[1];
    const float* W0  = (const float*)d_in[2];
    const float* b0  = (const float*)d_in[3];
    const float* g0  = (const float*)d_in[4];
    const float* bb0 = (const float*)d_in[5];
    const float* W1  = (const float*)d_in[6];
    const float* b1  = (const float*)d_in[7];
    const float* g1  = (const float*)d_in[8];
    const float* bb1 = (const float*)d_in[9];
    const float* fW0 = (const float*)d_in[10];
    const float* fb0 = (const float*)d_in[11];
    const float* fW1 = (const float*)d_in[12];
    const float* fb1 = (const float*)d_in[13];
    float* out = (float*)d_out;

    char* ws = (char*)d_ws;
    unsigned int* bitmap = (unsigned int*)ws;  ws += (size_t)NN * ROW_WORDS * 4;  // 12.8 MB
    float* deg    = (float*)ws;                ws += NN * 4;
    float* H1     = (float*)ws;                ws += (size_t)NN * 256 * 4;
    float* H2     = (float*)ws;                ws += (size_t)NN * 256 * 4;
    float* H3     = (float*)ws;                ws += (size_t)NN * 128 * 4;
    float* stats0 = (float*)ws;                ws += 512 * 4;
    float* stats1 = (float*)ws;                ws += 512 * 4;
    float* coeff0 = (float*)ws;                ws += 512 * 4;
    float* coeff1 = (float*)ws;                ws += 512 * 4;

    const int M = NN;

    hipMemsetAsync(bitmap, 0, (size_t)NN * ROW_WORDS * 4, stream);
    hipMemsetAsync(stats0, 0, 1024 * 4, stream);   // stats0 + stats1 (adjacent)
    scatter_bits<<<(NE + NN + 255) / 256, 256, 0, stream>>>(ei, bitmap);
    degree_kernel<<<(NN + 3) / 4, 256, 0, stream>>>(bitmap, deg);

    dim3 blk(256);
    const int gy = (M + 127) / 128;   // 79

    // conv0: H1 = relu((deg⊙x)@W0 + b0), stats0 accumulated
    gemm_fused<<<dim3(4, gy), blk, 0, stream>>>(x, W0, b0, deg, nullptr, nullptr,
                                                H1, stats0, M, 256, 500);
    bn_coeff<<<1, 256, 0, stream>>>(stats0, g0, bb0, coeff0, M, 256);

    // conv1: H2 = relu((deg⊙BN0(H1))@W1 + b1), stats1 accumulated
    gemm_fused<<<dim3(4, gy), blk, 0, stream>>>(H1, W1, b1, deg, coeff0, coeff0 + 256,
                                                H2, stats1, M, 256, 256);
    bn_coeff<<<1, 256, 0, stream>>>(stats1, g1, bb1, coeff1, M, 256);

    // fc0: H3 = relu(BN1(H2)@fW0 + fb0)
    gemm_fused<<<dim3(2, gy), blk, 0, stream>>>(H2, fW0, fb0, nullptr, coeff1, coeff1 + 256,
                                                H3, nullptr, M, 128, 256);
    // fc1: out = relu(H3@fW1 + fb1)
    gemm_fused<<<dim3(1, gy), blk, 0, stream>>>(H3, fW1, fb1, nullptr, nullptr, nullptr,
                                                out, nullptr, M, 40, 128);
}

// Round 3
// 240.596 us; speedup vs baseline: 1.8087x; 1.0878x over previous
//
#include <hip/hip_runtime.h>

#define NN 10000
#define NE 320000
#define ROW_WORDS 320   // 320*32 = 10240 bits >= 10000
#define MP 10112        // 79*128 padded rows

typedef __attribute__((ext_vector_type(8))) short short8;
typedef __attribute__((ext_vector_type(4))) float f32x4;
typedef unsigned short u16;

// ---------------- degree via dedup bitmap ----------------

__global__ void scatter_bits(const int* __restrict__ ei, unsigned int* __restrict__ bitmap) {
    int t = blockIdx.x * blockDim.x + threadIdx.x;
    if (t < NE) {
        int i = ei[t];
        int j = ei[NE + t];
        atomicOr(&bitmap[i * ROW_WORDS + (j >> 5)], 1u << (j & 31));
    } else if (t < NE + NN) {
        int i = t - NE;
        atomicOr(&bitmap[i * ROW_WORDS + (i >> 5)], 1u << (i & 31));
    }
}

__global__ void degree_kernel(const unsigned int* __restrict__ bitmap, float* __restrict__ deg) {
    int wave = threadIdx.x >> 6;
    int lane = threadIdx.x & 63;
    int row = blockIdx.x * 4 + wave;
    if (row >= NN) return;
    int cnt = 0;
    for (int w = lane; w < ROW_WORDS; w += 64)
        cnt += __popc(bitmap[row * ROW_WORDS + w]);
    #pragma unroll
    for (int off = 32; off > 0; off >>= 1)
        cnt += __shfl_down(cnt, off, 64);
    if (lane == 0) deg[row] = (float)cnt;
}

// ---------------- split helpers ----------------
__device__ __forceinline__ void split1(float v, u16& h, u16& l) {
    unsigned int u = __float_as_uint(v);
    h = (u16)(u >> 16);
    float hf = __uint_as_float(u & 0xFFFF0000u);
    l = (u16)(__float_as_uint(v - hf) >> 16);
}

__device__ __forceinline__ void gll16(const void* g, void* l) {
    __builtin_amdgcn_global_load_lds(
        (const __attribute__((address_space(1))) unsigned int*)g,
        (__attribute__((address_space(3))) unsigned int*)l, 16, 0, 0);
}

// ---------------- split_x: xhi/xlo[MP][512] = split(deg ⊙ x), zero-padded ----
__global__ void split_x(const float* __restrict__ x, const float* __restrict__ deg,
                        u16* __restrict__ xhi, u16* __restrict__ xlo) {
    int idx = blockIdx.x * blockDim.x + threadIdx.x;
    int r = idx >> 7;              // 128 threads per row (512/4)
    int k = (idx & 127) * 4;
    if (r >= MP) return;
    float vals[4] = {0.f, 0.f, 0.f, 0.f};
    if (r < NN && k < 500) {       // k multiple of 4, k<500 => k<=496 => k+3<=499 in-bounds
        float d = deg[r];
        float4 v = *(const float4*)&x[(size_t)r * 500 + k];
        vals[0] = v.x * d; vals[1] = v.y * d; vals[2] = v.z * d; vals[3] = v.w * d;
    }
    ushort4 hs, ls;
    split1(vals[0], hs.x, ls.x); split1(vals[1], hs.y, ls.y);
    split1(vals[2], hs.z, ls.z); split1(vals[3], hs.w, ls.w);
    *(ushort4*)&xhi[(size_t)r * 512 + k] = hs;
    *(ushort4*)&xlo[(size_t)r * 512 + k] = ls;
}

// ---------------- splitW: Wt_hi/lo[n][k] = split(sc_k * W[k][n]), transposed, padded
// grid (Kp/64, Np/64)
__global__ void splitW(const float* __restrict__ W, int K, int N,
                       const float* __restrict__ sc,
                       u16* __restrict__ Whi, u16* __restrict__ Wlo, int Kp) {
    __shared__ float tile[64][65];
    int t = threadIdx.x;
    int bk = blockIdx.x * 64, bn = blockIdx.y * 64;
    #pragma unroll
    for (int p = 0; p < 4; ++p) {
        int kk = (t >> 4) + p * 16;
        int nc = (t & 15) * 4;
        int k = bk + kk;
        float4 v = {0.f, 0.f, 0.f, 0.f};
        if (k < K && bn + nc + 3 < N) {
            v = *(const float4*)&W[(size_t)k * N + bn + nc];
            float s = sc ? sc[k] : 1.f;
            v.x *= s; v.y *= s; v.z *= s; v.w *= s;
        }
        tile[kk][nc] = v.x; tile[kk][nc + 1] = v.y;
        tile[kk][nc + 2] = v.z; tile[kk][nc + 3] = v.w;
    }
    __syncthreads();
    int nn = t >> 2;
    int kk0 = (t & 3) * 16;
    u16 hs[16], ls[16];
    #pragma unroll
    for (int j = 0; j < 16; ++j) split1(tile[kk0 + j][nn], hs[j], ls[j]);
    size_t ob = (size_t)(bn + nn) * Kp + bk + kk0;
    *(short8*)&Whi[ob] = *(short8*)hs;
    *(short8*)&Whi[ob + 8] = *(short8*)&hs[8];
    *(short8*)&Wlo[ob] = *(short8*)ls;
    *(short8*)&Wlo[ob + 8] = *(short8*)&ls[8];
}

// ---------------- colvec: out[n] = base[n] + sum_k sh[k] * W[k][n]; grid N/64
__global__ void colvec(const float* __restrict__ W, const float* __restrict__ sh,
                       const float* __restrict__ base, float* __restrict__ out,
                       int K, int N) {
    __shared__ float red[4][64];
    int nl = threadIdx.x & 63;
    int n = blockIdx.x * 64 + nl;
    int kq = threadIdx.x >> 6;
    float s = 0.f;
    for (int k = kq; k < K; k += 4) s += sh[k] * W[(size_t)k * N + n];
    red[kq][nl] = s;
    __syncthreads();
    if (kq == 0) out[n] = (base ? base[n] : 0.f) + red[0][nl] + red[1][nl] + red[2][nl] + red[3][nl];
}

// ---------------- BN coefficients ----------------
__global__ void bn_coeff(const float* __restrict__ stats, const float* __restrict__ g,
                         const float* __restrict__ b, float* __restrict__ coeff,
                         int M, int N) {
    int j = threadIdx.x;
    if (j >= N) return;
    float mean = stats[j] / (float)M;
    float var  = stats[N + j] / (float)M - mean * mean;
    float scl = g[j] * rsqrtf(var + 1e-5f);
    coeff[j] = scl;
    coeff[N + j] = b[j] - mean * scl;
}

// ---------------- main GEMM ----------------
// C = relu( A@B + bias + [deg_r*cvec_n] ), A=[Mp][Kp] hi/lo bf16 (row,k-fast),
// B=[Np][Kp] hi/lo bf16 (col,k-fast). BM=RT*64, BN=64, BK=64, 256 thr = 4 waves.
// degmode: 0 none; 1 output scaled by deg_r (conv0); 2 add deg_r*cvec (conv1).
// Output: split hi/lo [.][No] (pad rows zeroed) or fp32 Ofp [M][No].
template<int RT>
__global__ __launch_bounds__(256, 2)
void gemm_split(const u16* __restrict__ Ahi, const u16* __restrict__ Alo,
                const u16* __restrict__ Bhi, const u16* __restrict__ Blo,
                int Kp, int M, int N,
                const float* __restrict__ bias, const float* __restrict__ cvec,
                const float* __restrict__ deg, int degmode,
                float* __restrict__ stats,
                u16* __restrict__ Ohi, u16* __restrict__ Olo,
                float* __restrict__ Ofp, int No) {
    constexpr int NA  = RT * 8;          // wave-loads per A region
    constexpr int PW  = (2 * NA + 16) / 4;
    constexpr int SA  = RT * 64 * 128;   // bytes per A region
    constexpr int SB  = 64 * 128;
    __shared__ char smem[2 * SA + 2 * SB];

    const int t = threadIdx.x;
    const int lane = t & 63;
    const int w = t >> 6;
    const int q = lane >> 4;
    const int l16 = lane & 15;
    const int m7 = l16 & 7;
    const int row0 = blockIdx.y * (RT * 64);
    const int col0 = blockIdx.x * 64;

    // staging descriptors: wave-load gi = w + i*4
    const u16* srcs[PW];
    char* dsts[PW];
    #pragma unroll
    for (int i = 0; i < PW; ++i) {
        int gi = w + i * 4;
        const u16* base;
        char* dst;
        int rb;
        int j;
        if (gi < NA)            { base = Ahi; j = gi;           dst = smem + j * 1024;           rb = row0; }
        else if (gi < 2 * NA)   { base = Alo; j = gi - NA;      dst = smem + SA + j * 1024;      rb = row0; }
        else if (gi < 2*NA + 8) { base = Bhi; j = gi - 2 * NA;  dst = smem + 2*SA + j * 1024;    rb = col0; }
        else                    { base = Blo; j = gi - 2*NA - 8; dst = smem + 2*SA + SB + j*1024; rb = col0; }
        int r = j * 8 + (lane >> 3);
        int c = (lane & 7) ^ (r & 7);
        srcs[i] = base + (size_t)(rb + r) * Kp + c * 8;
        dsts[i] = dst;
    }

    f32x4 acc[RT][4];
    #pragma unroll
    for (int g = 0; g < RT; ++g)
        #pragma unroll
        for (int s = 0; s < 4; ++s) acc[g][s] = (f32x4){0.f, 0.f, 0.f, 0.f};

    // issue first tile's loads
    #pragma unroll
    for (int i = 0; i < PW; ++i) { gll16(srcs[i], dsts[i]); srcs[i] += 64; }

    for (int k0 = 0; k0 < Kp; k0 += 64) {
        __syncthreads();                       // drain vmcnt: tile resident
        short8 ah[2][RT], al[2][RT], bh[2][4], bl[2][4];
        #pragma unroll
        for (int kc = 0; kc < 2; ++kc) {
            #pragma unroll
            for (int g = 0; g < RT; ++g) {
                int r = w * (RT * 16) + g * 16 + l16;
                int off = r * 128 + (((kc * 4 + q) ^ m7) * 16);
                ah[kc][g] = *(const short8*)(smem + off);
                al[kc][g] = *(const short8*)(smem + SA + off);
            }
            #pragma unroll
            for (int s = 0; s < 4; ++s) {
                int n = s * 16 + l16;
                int off = n * 128 + (((kc * 4 + q) ^ m7) * 16);
                bh[kc][s] = *(const short8*)(smem + 2 * SA + off);
                bl[kc][s] = *(const short8*)(smem + 2 * SA + SB + off);
            }
        }
        __syncthreads();                       // all waves done reading LDS
        if (k0 + 64 < Kp) {                    // prefetch next tile; overlaps MFMA below
            #pragma unroll
            for (int i = 0; i < PW; ++i) { gll16(srcs[i], dsts[i]); srcs[i] += 64; }
        }
        #pragma unroll
        for (int kc = 0; kc < 2; ++kc)
            #pragma unroll
            for (int g = 0; g < RT; ++g)
                #pragma unroll
                for (int s = 0; s < 4; ++s) {
                    acc[g][s] = __builtin_amdgcn_mfma_f32_16x16x32_bf16(al[kc][g], bh[kc][s], acc[g][s], 0, 0, 0);
                    acc[g][s] = __builtin_amdgcn_mfma_f32_16x16x32_bf16(ah[kc][g], bl[kc][s], acc[g][s], 0, 0, 0);
                    acc[g][s] = __builtin_amdgcn_mfma_f32_16x16x32_bf16(ah[kc][g], bh[kc][s], acc[g][s], 0, 0, 0);
                }
    }

    // ---- epilogue ----
    #pragma unroll
    for (int g = 0; g < RT; ++g) {
        int growb = row0 + w * (RT * 16) + g * 16 + q * 4;
        float dgv[4];
        #pragma unroll
        for (int r = 0; r < 4; ++r)
            dgv[r] = degmode ? ((growb + r < M) ? deg[growb + r] : 0.f) : 1.f;
        #pragma unroll
        for (int s = 0; s < 4; ++s) {
            int gc = col0 + s * 16 + l16;
            float bia = (gc < N) ? bias[gc] : 0.f;
            float cv = (cvec && gc < N) ? cvec[gc] : 0.f;
            float s_sum = 0.f, ss_sum = 0.f;
            #pragma unroll
            for (int r = 0; r < 4; ++r) {
                int grow = growb + r;
                bool real = (grow < M) && (gc < N);
                float pre = acc[g][s][r] + bia;
                if (degmode == 2) pre += dgv[r] * cv;
                float v = fmaxf(pre, 0.f);
                if (!real) v = 0.f;
                s_sum += v; ss_sum += v * v;
                if (Ofp) {
                    if (real) Ofp[(size_t)grow * No + gc] = v;
                } else {
                    float vo = (degmode == 1) ? v * dgv[r] : v;
                    u16 h, l; split1(vo, h, l);
                    Ohi[(size_t)grow * No + gc] = h;
                    Olo[(size_t)grow * No + gc] = l;
                }
            }
            if (stats) {
                s_sum  += __shfl_xor(s_sum, 16);  s_sum  += __shfl_xor(s_sum, 32);
                ss_sum += __shfl_xor(ss_sum, 16); ss_sum += __shfl_xor(ss_sum, 32);
                if (lane < 16 && gc < N) {
                    atomicAdd(&stats[gc], s_sum);
                    atomicAdd(&stats[N + gc], ss_sum);
                }
            }
        }
    }
}

// ---------------- launch ----------------

extern "C" void kernel_launch(void* const* d_in, const int* in_sizes, int n_in,
                              void* d_out, int out_size, void* d_ws, size_t ws_size,
                              hipStream_t stream) {
    const float* x   = (const float*)d_in[0];
    const int*   ei  = (const int*)d_in[1];
    const float* W0  = (const float*)d_in[2];
    const float* b0  = (const float*)d_in[3];
    const float* g0  = (const float*)d_in[4];
    const float* bb0 = (const float*)d_in[5];
    const float* W1  = (const float*)d_in[6];
    const float* b1  = (const float*)d_in[7];
    const float* g1  = (const float*)d_in[8];
    const float* bb1 = (const float*)d_in[9];
    const float* fW0 = (const float*)d_in[10];
    const float* fb0 = (const float*)d_in[11];
    const float* fW1 = (const float*)d_in[12];
    const float* fb1 = (const float*)d_in[13];
    float* out = (float*)d_out;

    char* ws = (char*)d_ws;
    auto carve = [&](size_t bytes) { char* p = ws; ws += (bytes + 255) & ~(size_t)255; return p; };

    // bitmap region (12.8 MB) reused for H1 hi/lo (10.35 MB) after degree pass
    char* region0 = carve((size_t)NN * ROW_WORDS * 4);
    unsigned int* bitmap = (unsigned int*)region0;
    u16* H1hi = (u16*)region0;
    u16* H1lo = (u16*)(region0 + (size_t)MP * 256 * 2);

    float* deg   = (float*)carve(MP * 4);
    u16* xhi     = (u16*)carve((size_t)MP * 512 * 2);
    u16* xlo     = (u16*)carve((size_t)MP * 512 * 2);
    u16* W0thi   = (u16*)carve(256 * 512 * 2);
    u16* W0tlo   = (u16*)carve(256 * 512 * 2);
    u16* W1thi   = (u16*)carve(256 * 256 * 2);
    u16* W1tlo   = (u16*)carve(256 * 256 * 2);
    u16* fW0thi  = (u16*)carve(128 * 256 * 2);
    u16* fW0tlo  = (u16*)carve(128 * 256 * 2);
    u16* fW1thi  = (u16*)carve(64 * 128 * 2);
    u16* fW1tlo  = (u16*)carve(64 * 128 * 2);
    u16* H2hi    = (u16*)carve((size_t)MP * 256 * 2);
    u16* H2lo    = (u16*)carve((size_t)MP * 256 * 2);
    u16* H3hi    = (u16*)carve((size_t)MP * 128 * 2);
    u16* H3lo    = (u16*)carve((size_t)MP * 128 * 2);
    float* stats = (float*)carve(1024 * 4);    // stats0 [0,512), stats1 [512,1024)
    float* coeff0 = (float*)carve(512 * 4);
    float* coeff1 = (float*)carve(512 * 4);
    float* cvec1  = (float*)carve(256 * 4);
    float* biasf0 = (float*)carve(128 * 4);

    const int M = NN;
    dim3 blk(256);

    hipMemsetAsync(bitmap, 0, (size_t)NN * ROW_WORDS * 4, stream);
    hipMemsetAsync(stats, 0, 1024 * 4, stream);
    scatter_bits<<<(NE + NN + 255) / 256, 256, 0, stream>>>(ei, bitmap);
    degree_kernel<<<(NN + 3) / 4, 256, 0, stream>>>(bitmap, deg);

    split_x<<<(MP * 128 + 255) / 256, blk, 0, stream>>>(x, deg, xhi, xlo);
    splitW<<<dim3(8, 4), blk, 0, stream>>>(W0, 500, 256, nullptr, W0thi, W0tlo, 512);
    splitW<<<dim3(2, 1), blk, 0, stream>>>(fW1, 128, 40, nullptr, fW1thi, fW1tlo, 128);

    // conv0: H1 = deg ⊙ relu((deg⊙x)@W0 + b0); stats0 over relu output
    gemm_split<2><<<dim3(4, 79), blk, 0, stream>>>(
        xhi, xlo, W0thi, W0tlo, 512, M, 256, b0, nullptr, deg, 1, stats,
        H1hi, H1lo, nullptr, 256);
    bn_coeff<<<1, 256, 0, stream>>>(stats, g0, bb0, coeff0, M, 256);

    // fold BN0 into W1: B = sc0⊙W1 (split), cvec1 = sh0·W1
    splitW<<<dim3(4, 4), blk, 0, stream>>>(W1, 256, 256, coeff0, W1thi, W1tlo, 256);
    colvec<<<4, blk, 0, stream>>>(W1, coeff0 + 256, nullptr, cvec1, 256, 256);

    // conv1: H2 = relu(H1@(sc0⊙W1) + deg*cvec1 + b1); stats1
    gemm_split<2><<<dim3(4, 79), blk, 0, stream>>>(
        H1hi, H1lo, W1thi, W1tlo, 256, M, 256, b1, cvec1, deg, 2, stats + 512,
        H2hi, H2lo, nullptr, 256);
    bn_coeff<<<1, 256, 0, stream>>>(stats + 512, g1, bb1, coeff1, M, 256);

    // fold BN1 into fW0: B = sc1⊙fW0, bias = fb0 + sh1·fW0
    splitW<<<dim3(4, 2), blk, 0, stream>>>(fW0, 256, 128, coeff1, fW0thi, fW0tlo, 256);
    colvec<<<2, blk, 0, stream>>>(fW0, coeff1 + 256, fb0, biasf0, 256, 128);

    // fc0: H3 = relu(H2@(sc1⊙fW0) + biasf0)
    gemm_split<1><<<dim3(2, 157), blk, 0, stream>>>(
        H2hi, H2lo, fW0thi, fW0tlo, 256, M, 128, biasf0, nullptr, nullptr, 0, nullptr,
        H3hi, H3lo, nullptr, 128);

    // fc1: out = relu(H3@fW1 + fb1), fp32, N=40
    gemm_split<1><<<dim3(1, 157), blk, 0, stream>>>(
        H3hi, H3lo, fW1thi, fW1tlo, 128, M, 40, fb1, nullptr, nullptr, 0, nullptr,
        nullptr, nullptr, out, 40);
}

// Round 4
// 225.180 us; speedup vs baseline: 1.9325x; 1.0685x over previous
//
#include <hip/hip_runtime.h>

#define NN 10000
#define NE 320000
#define ROW_WORDS 320   // 320*32 = 10240 bits >= 10000
#define MP 10112        // 158*64 padded rows
#define BN_EPS 1e-5f

typedef __attribute__((ext_vector_type(8))) short short8;
typedef __attribute__((ext_vector_type(4))) float f32x4;
typedef unsigned short u16;

// ---------------- helpers ----------------
__device__ __forceinline__ void split1(float v, u16& h, u16& l) {
    unsigned int u = __float_as_uint(v);
    h = (u16)(u >> 16);
    float hf = __uint_as_float(u & 0xFFFF0000u);
    l = (u16)(__float_as_uint(v - hf) >> 16);
}

__device__ __forceinline__ void gll16(const void* g, void* l) {
    __builtin_amdgcn_global_load_lds(
        (const __attribute__((address_space(1))) unsigned int*)g,
        (__attribute__((address_space(3))) unsigned int*)l, 16, 0, 0);
}

// ---------------- edge scatter (dedup bitmap) ----------------
__global__ void scatter_bits(const int* __restrict__ ei, unsigned int* __restrict__ bitmap) {
    int t = blockIdx.x * blockDim.x + threadIdx.x;
    if (t < NE) {
        int i = ei[t];
        int j = ei[NE + t];
        atomicOr(&bitmap[i * ROW_WORDS + (j >> 5)], 1u << (j & 31));
    } else if (t < NE + NN) {
        int i = t - NE;
        atomicOr(&bitmap[i * ROW_WORDS + (i >> 5)], 1u << (i & 31));
    }
}

// ---------------- splitW device fn: Wt[n][k] = split(scale_k * W[k][n]) ----------------
// scale_k = 1 (stats==null) or BN scale g_k*rsqrt(var_k+eps) computed from raw stats.
__device__ void splitW_dev(const float* __restrict__ W, int K, int N, int Kp, int Np,
                           const float* __restrict__ stats, const float* __restrict__ g,
                           u16* __restrict__ Wt, int bx, int by) {
    __shared__ float tile[64][65];
    int t = threadIdx.x;
    int bk = bx * 64, bn = by * 64;
    const float invM = 1.f / (float)NN;
    #pragma unroll
    for (int p = 0; p < 4; ++p) {
        int kk = (t >> 4) + p * 16;
        int nc = (t & 15) * 4;
        int k = bk + kk;
        float4 v = {0.f, 0.f, 0.f, 0.f};
        if (k < K && bn + nc + 3 < N) {
            v = *(const float4*)&W[(size_t)k * N + bn + nc];
            float s = 1.f;
            if (stats) {
                float mean = stats[k] * invM;
                float var = stats[256 + k] * invM - mean * mean;
                s = g[k] * rsqrtf(var + BN_EPS);
            }
            v.x *= s; v.y *= s; v.z *= s; v.w *= s;
        }
        tile[kk][nc] = v.x; tile[kk][nc + 1] = v.y;
        tile[kk][nc + 2] = v.z; tile[kk][nc + 3] = v.w;
    }
    __syncthreads();
    int nn = t >> 2;
    int kk0 = (t & 3) * 16;
    u16 hs[16], ls[16];
    #pragma unroll
    for (int j = 0; j < 16; ++j) split1(tile[kk0 + j][nn], hs[j], ls[j]);
    size_t ob = (size_t)(bn + nn) * Kp + bk + kk0;
    size_t lo = (size_t)Np * Kp;
    *(short8*)&Wt[ob] = *(short8*)hs;
    *(short8*)&Wt[ob + 8] = *(short8*)&hs[8];
    *(short8*)&Wt[lo + ob] = *(short8*)ls;
    *(short8*)&Wt[lo + ob + 8] = *(short8*)&ls[8];
}

// ---------------- colvec device fn: out[n] = base[n] + sum_k sh_k * W[k][n] ----------------
// sh_k = bb_k - mean_k * (g_k*rsqrt(var_k+eps)), from raw stats.
__device__ void colvec_dev(const float* __restrict__ W, int K, int N,
                           const float* __restrict__ stats, const float* __restrict__ g,
                           const float* __restrict__ bb, const float* __restrict__ base,
                           float* __restrict__ outv, int cb) {
    __shared__ float red[4][64];
    int nl = threadIdx.x & 63;
    int n = cb * 64 + nl;
    int kq = threadIdx.x >> 6;
    const float invM = 1.f / (float)NN;
    float s = 0.f;
    for (int k = kq; k < K; k += 4) {
        float mean = stats[k] * invM;
        float var = stats[256 + k] * invM - mean * mean;
        float scl = g[k] * rsqrtf(var + BN_EPS);
        float sh = bb[k] - mean * scl;
        s += sh * W[(size_t)k * N + n];
    }
    red[kq][nl] = s;
    __syncthreads();
    if (kq == 0 && n < N)
        outv[n] = (base ? base[n] : 0.f) + red[0][nl] + red[1][nl] + red[2][nl] + red[3][nl];
}

// ---------------- prep: degree + split_x + splitW(W0) + splitW(fW1) ----------------
__global__ __launch_bounds__(256)
void prep(const unsigned int* __restrict__ bitmap, const float* __restrict__ x,
          const float* __restrict__ W0, const float* __restrict__ fW1,
          float* __restrict__ deg, u16* __restrict__ xs,
          u16* __restrict__ W0t, u16* __restrict__ fW1t) {
    int b = blockIdx.x;
    if (b < 632) {
        __shared__ float sdeg[16];
        int t = threadIdx.x;
        int r = t >> 4, l = t & 15;
        int grow = b * 16 + r;
        int cnt = 0;
        if (grow < NN)
            for (int w = l; w < ROW_WORDS; w += 16)
                cnt += __popc(bitmap[grow * ROW_WORDS + w]);
        cnt += __shfl_down(cnt, 8, 16);
        cnt += __shfl_down(cnt, 4, 16);
        cnt += __shfl_down(cnt, 2, 16);
        cnt += __shfl_down(cnt, 1, 16);
        if (l == 0) {
            sdeg[r] = (float)cnt;
            if (grow < NN) deg[grow] = (float)cnt;
        }
        __syncthreads();
        float d = sdeg[r];
        u16* xlo = xs + (size_t)MP * 512;
        #pragma unroll
        for (int j = 0; j < 8; ++j) {
            int k = (l + j * 16) * 4;
            float vals[4] = {0.f, 0.f, 0.f, 0.f};
            if (grow < NN && k < 500) {
                float4 v = *(const float4*)&x[(size_t)grow * 500 + k];
                vals[0] = v.x * d; vals[1] = v.y * d; vals[2] = v.z * d; vals[3] = v.w * d;
            }
            ushort4 hs, ls;
            split1(vals[0], hs.x, ls.x); split1(vals[1], hs.y, ls.y);
            split1(vals[2], hs.z, ls.z); split1(vals[3], hs.w, ls.w);
            *(ushort4*)&xs[(size_t)grow * 512 + k] = hs;
            *(ushort4*)&xlo[(size_t)grow * 512 + k] = ls;
        }
    } else if (b < 664) {
        int idx = b - 632;
        splitW_dev(W0, 500, 256, 512, 256, nullptr, nullptr, W0t, idx & 7, idx >> 3);
    } else {
        splitW_dev(fW1, 128, 40, 128, 64, nullptr, nullptr, fW1t, b - 664, 0);
    }
}

// ---------------- post: BN-fold weight split + shift colvec ----------------
__global__ __launch_bounds__(256)
void post(const float* __restrict__ W, int K, int N, int Kp, int Np,
          const float* __restrict__ stats, const float* __restrict__ g,
          const float* __restrict__ bb, u16* __restrict__ Wt,
          int ntiles, int tx, const float* __restrict__ cvbase, float* __restrict__ cvout) {
    int b = blockIdx.x;
    if (b < ntiles)
        splitW_dev(W, K, N, Kp, Np, stats, g, Wt, b % tx, b / tx);
    else
        colvec_dev(W, K, N, stats, g, bb, cvbase, cvout, b - ntiles);
}

// ---------------- main GEMM: BM=64, BN=64, BK=64, 256 thr = 4 waves ----------------
// C = relu( A@B + bias + [deg_r*cvec_n] ); A=[MP][Kp] hi|lo bf16, B=[Np][Kp] hi|lo.
// degmode: 0 none; 1 scale stored output by deg_r (conv0); 2 add deg_r*cvec_n (conv1).
__global__ __launch_bounds__(256, 3)
void gemm_split(const u16* __restrict__ Ahi, const u16* __restrict__ Alo,
                const u16* __restrict__ Bhi, const u16* __restrict__ Blo,
                int Kp, int M, int N,
                const float* __restrict__ bias, const float* __restrict__ cvec,
                const float* __restrict__ deg, int degmode,
                float* __restrict__ stats,
                u16* __restrict__ Ohi, u16* __restrict__ Olo,
                float* __restrict__ Ofp, int No) {
    __shared__ char smem[4 * 8192];   // Ahi | Alo | Bhi | Blo, each 64x64 bf16

    const int t = threadIdx.x;
    const int lane = t & 63;
    const int w = t >> 6;
    const int q = lane >> 4;
    const int l16 = lane & 15;
    const int m7 = l16 & 7;
    const int row0 = blockIdx.y * 64;
    const int col0 = blockIdx.x * 64;

    const u16* bases[4] = {Ahi, Alo, Bhi, Blo};
    const u16* srcs[8];
    unsigned dstoff[8];
    #pragma unroll
    for (int i = 0; i < 8; ++i) {
        int gi = w + i * 4;
        int reg = i >> 1;
        int j = gi & 7;
        int rb = (reg < 2) ? row0 : col0;
        int r = j * 8 + (lane >> 3);
        int c = (lane & 7) ^ (r & 7);
        srcs[i] = bases[reg] + (size_t)(rb + r) * Kp + c * 8;
        dstoff[i] = reg * 8192 + j * 1024;
    }

    f32x4 acc[4];
    #pragma unroll
    for (int s = 0; s < 4; ++s) acc[s] = (f32x4){0.f, 0.f, 0.f, 0.f};

    #pragma unroll
    for (int i = 0; i < 8; ++i) { gll16(srcs[i], smem + dstoff[i]); srcs[i] += 64; }

    for (int k0 = 0; k0 < Kp; k0 += 64) {
        __syncthreads();                       // drain loads: tile resident
        short8 ah[2], al[2], bh[2][4], bl[2][4];
        #pragma unroll
        for (int kc = 0; kc < 2; ++kc) {
            int aoff = (w * 16 + l16) * 128 + (((kc * 4 + q) ^ m7) * 16);
            ah[kc] = *(const short8*)(smem + aoff);
            al[kc] = *(const short8*)(smem + 8192 + aoff);
            #pragma unroll
            for (int s = 0; s < 4; ++s) {
                int boff = (s * 16 + l16) * 128 + (((kc * 4 + q) ^ m7) * 16);
                bh[kc][s] = *(const short8*)(smem + 16384 + boff);
                bl[kc][s] = *(const short8*)(smem + 24576 + boff);
            }
        }
        __syncthreads();                       // all waves done reading LDS
        if (k0 + 64 < Kp) {                    // prefetch next tile; overlaps MFMA
            #pragma unroll
            for (int i = 0; i < 8; ++i) { gll16(srcs[i], smem + dstoff[i]); srcs[i] += 64; }
        }
        #pragma unroll
        for (int kc = 0; kc < 2; ++kc)
            #pragma unroll
            for (int s = 0; s < 4; ++s) {
                acc[s] = __builtin_amdgcn_mfma_f32_16x16x32_bf16(al[kc], bh[kc][s], acc[s], 0, 0, 0);
                acc[s] = __builtin_amdgcn_mfma_f32_16x16x32_bf16(ah[kc], bl[kc][s], acc[s], 0, 0, 0);
                acc[s] = __builtin_amdgcn_mfma_f32_16x16x32_bf16(ah[kc], bh[kc][s], acc[s], 0, 0, 0);
            }
    }

    // ---- epilogue: bias (+deg*cvec) + relu + store + column stats ----
    int growb = row0 + w * 16 + q * 4;
    float dgv[4];
    #pragma unroll
    for (int r = 0; r < 4; ++r)
        dgv[r] = degmode ? ((growb + r < M) ? deg[growb + r] : 0.f) : 1.f;
    #pragma unroll
    for (int s = 0; s < 4; ++s) {
        int gc = col0 + s * 16 + l16;
        float bia = (gc < N) ? bias[gc] : 0.f;
        float cv = (cvec && gc < N) ? cvec[gc] : 0.f;
        float s_sum = 0.f, ss_sum = 0.f;
        #pragma unroll
        for (int r = 0; r < 4; ++r) {
            int grow = growb + r;
            bool real = (grow < M) && (gc < N);
            float pre = acc[s][r] + bia;
            if (degmode == 2) pre += dgv[r] * cv;
            float v = fmaxf(pre, 0.f);
            if (!real) v = 0.f;
            s_sum += v; ss_sum += v * v;
            if (Ofp) {
                if (real) Ofp[(size_t)grow * No + gc] = v;
            } else {
                float vo = (degmode == 1) ? v * dgv[r] : v;
                u16 h, l; split1(vo, h, l);
                Ohi[(size_t)grow * No + gc] = h;
                Olo[(size_t)grow * No + gc] = l;
            }
        }
        if (stats) {
            s_sum  += __shfl_xor(s_sum, 16);  s_sum  += __shfl_xor(s_sum, 32);
            ss_sum += __shfl_xor(ss_sum, 16); ss_sum += __shfl_xor(ss_sum, 32);
            if (lane < 16 && gc < N) {
                atomicAdd(&stats[gc], s_sum);
                atomicAdd(&stats[256 + gc], ss_sum);
            }
        }
    }
}

// ---------------- launch ----------------

extern "C" void kernel_launch(void* const* d_in, const int* in_sizes, int n_in,
                              void* d_out, int out_size, void* d_ws, size_t ws_size,
                              hipStream_t stream) {
    const float* x   = (const float*)d_in[0];
    const int*   ei  = (const int*)d_in[1];
    const float* W0  = (const float*)d_in[2];
    const float* b0  = (const float*)d_in[3];
    const float* g0  = (const float*)d_in[4];
    const float* bb0 = (const float*)d_in[5];
    const float* W1  = (const float*)d_in[6];
    const float* b1  = (const float*)d_in[7];
    const float* g1  = (const float*)d_in[8];
    const float* bb1 = (const float*)d_in[9];
    const float* fW0 = (const float*)d_in[10];
    const float* fb0 = (const float*)d_in[11];
    const float* fW1 = (const float*)d_in[12];
    const float* fb1 = (const float*)d_in[13];
    float* out = (float*)d_out;

    char* ws = (char*)d_ws;
    auto carve = [&](size_t bytes) { char* p = ws; ws += (bytes + 255) & ~(size_t)255; return p; };

    // region0: bitmap (12.8 MB) + stats (4 KB); bitmap reused for H1 hi|lo (10.35 MB)
    const size_t BITMAP_BYTES = (size_t)NN * ROW_WORDS * 4;   // 12,800,000
    char* region0 = carve(BITMAP_BYTES + 4096);
    unsigned int* bitmap = (unsigned int*)region0;
    float* stats = (float*)(region0 + BITMAP_BYTES);          // stats0 [0,512), stats1 [512,1024)
    u16* H1 = (u16*)region0;                                  // hi | lo, each MP*256

    float* deg  = (float*)carve(MP * 4);
    u16* xs     = (u16*)carve((size_t)2 * MP * 512 * 2);      // hi | lo
    u16* W0t    = (u16*)carve((size_t)2 * 256 * 512 * 2);
    u16* W1t    = (u16*)carve((size_t)2 * 256 * 256 * 2);
    u16* fW0t   = (u16*)carve((size_t)2 * 128 * 256 * 2);
    u16* fW1t   = (u16*)carve((size_t)2 * 64 * 128 * 2);
    u16* H2     = (u16*)carve((size_t)2 * MP * 256 * 2);
    u16* H3     = (u16*)carve((size_t)2 * MP * 128 * 2);
    float* cvec1  = (float*)carve(256 * 4);
    float* biasf0 = (float*)carve(128 * 4);

    const int M = NN;
    dim3 blk(256);

    // 1. zero bitmap + stats in one fill
    hipMemsetAsync(region0, 0, BITMAP_BYTES + 4096, stream);
    // 2. edge scatter
    scatter_bits<<<(NE + NN + 255) / 256, blk, 0, stream>>>(ei, bitmap);
    // 3. degree + split x + split W0 + split fW1
    prep<<<666, blk, 0, stream>>>(bitmap, x, W0, fW1, deg, xs, W0t, fW1t);

    // 4. conv0: H1 = deg ⊙ relu((deg⊙x)@W0 + b0); stats0 over relu output
    gemm_split<<<dim3(4, 158), blk, 0, stream>>>(
        xs, xs + (size_t)MP * 512, W0t, W0t + 256 * 512, 512, M, 256,
        b0, nullptr, deg, 1, stats, H1, H1 + (size_t)MP * 256, nullptr, 256);

    // 5. fold BN0 into W1 (scale) + cvec1 (shift)
    post<<<20, blk, 0, stream>>>(W1, 256, 256, 256, 256, stats, g0, bb0, W1t,
                                 16, 4, nullptr, cvec1);

    // 6. conv1: H2 = relu(H1@(sc0⊙W1) + deg*cvec1 + b1); stats1
    gemm_split<<<dim3(4, 158), blk, 0, stream>>>(
        H1, H1 + (size_t)MP * 256, W1t, W1t + 256 * 256, 256, M, 256,
        b1, cvec1, deg, 2, stats + 512, H2, H2 + (size_t)MP * 256, nullptr, 256);

    // 7. fold BN1 into fW0 (scale) + biasf0 = fb0 + shift·fW0
    post<<<10, blk, 0, stream>>>(fW0, 256, 128, 256, 128, stats + 512, g1, bb1, fW0t,
                                 8, 4, fb0, biasf0);

    // 8. fc0: H3 = relu(H2@(sc1⊙fW0) + biasf0)
    gemm_split<<<dim3(2, 158), blk, 0, stream>>>(
        H2, H2 + (size_t)MP * 256, fW0t, fW0t + 128 * 256, 256, M, 128,
        biasf0, nullptr, nullptr, 0, nullptr, H3, H3 + (size_t)MP * 128, nullptr, 128);

    // 9. fc1: out = relu(H3@fW1 + fb1), fp32
    gemm_split<<<dim3(1, 158), blk, 0, stream>>>(
        H3, H3 + (size_t)MP * 128, fW1t, fW1t + 64 * 128, 128, M, 40,
        fb1, nullptr, nullptr, 0, nullptr, nullptr, nullptr, out, 40);
}